// Round 1
// baseline (1656.815 us; speedup 1.0000x reference)
//
#include <hip/hip_runtime.h>

#define T_TOK 4096
#define H_DIM 2048
#define I_DIM 4096
#define N_EXP 8

typedef __attribute__((ext_vector_type(8))) short bf16x8;     // MFMA A/B frag (8 bf16)
typedef __attribute__((ext_vector_type(4))) float f32x4;      // MFMA C/D frag
typedef __attribute__((ext_vector_type(8))) unsigned short u16x8;

__device__ __forceinline__ unsigned short f2bf(float x) {
    union { float f; unsigned u; } v; v.f = x;
    unsigned r = v.u + 0x7FFF + ((v.u >> 16) & 1);   // RNE
    return (unsigned short)(r >> 16);
}

// ---------------- routing: top-2 + softmax + bucketize (single block) ----------
__global__ void routing_kernel(const float* __restrict__ logits,
                               int* __restrict__ counts, int* __restrict__ offsets,
                               int* __restrict__ btok, float* __restrict__ bw) {
    __shared__ int s_cnt[N_EXP];
    __shared__ int s_off[N_EXP];
    __shared__ int s_cur[N_EXP];
    const int tid = threadIdx.x;   // 256 threads, 16 tokens each
    if (tid < N_EXP) s_cnt[tid] = 0;
    __syncthreads();

    int e0a[16], e1a[16]; float w0a[16], w1a[16];
    #pragma unroll
    for (int it = 0; it < 16; ++it) {
        int t = tid + it * 256;
        float l[8];
        #pragma unroll
        for (int e = 0; e < 8; ++e) l[e] = logits[t * 8 + e];
        int b0 = 0; float v0 = l[0];
        #pragma unroll
        for (int e = 1; e < 8; ++e) if (l[e] > v0) { v0 = l[e]; b0 = e; }
        int b1 = (b0 == 0) ? 1 : 0; float v1 = l[b1];
        #pragma unroll
        for (int e = 0; e < 8; ++e) if (e != b0 && l[e] > v1) { v1 = l[e]; b1 = e; }
        float w0 = 1.0f / (1.0f + __expf(v1 - v0));
        e0a[it] = b0; e1a[it] = b1; w0a[it] = w0; w1a[it] = 1.0f - w0;
        atomicAdd(&s_cnt[b0], 1);
        atomicAdd(&s_cnt[b1], 1);
    }
    __syncthreads();
    if (tid == 0) {
        int acc = 0;
        for (int e = 0; e < N_EXP; ++e) { s_off[e] = acc; s_cur[e] = acc; acc += s_cnt[e]; }
    }
    __syncthreads();
    if (tid < N_EXP) { counts[tid] = s_cnt[tid]; offsets[tid] = s_off[tid]; }
    #pragma unroll
    for (int it = 0; it < 16; ++it) {
        int t = tid + it * 256;
        int p0 = atomicAdd(&s_cur[e0a[it]], 1);
        btok[p0] = t; bw[p0] = w0a[it];
        int p1 = atomicAdd(&s_cur[e1a[it]], 1);
        btok[p1] = t; bw[p1] = w1a[it];
    }
}

// ---------------- fp32 -> bf16 convert of hidden_states ----------------------
__global__ void cvt_kernel(const float* __restrict__ x, unsigned short* __restrict__ xb) {
    int i = blockIdx.x * blockDim.x + threadIdx.x;   // over float4s
    float4 v = ((const float4*)x)[i];
    ushort4 o;
    o.x = f2bf(v.x); o.y = f2bf(v.y); o.z = f2bf(v.z); o.w = f2bf(v.w);
    ((ushort4*)xb)[i] = o;
}

// ---------------- GEMM1: gate/up fused, silu epilogue ------------------------
// C tile 128x128, K-step 32, 4 waves (2x2), each wave 64x64 via 4x4 16x16x32 MFMA.
__global__ __launch_bounds__(256, 2)
void gemm1_kernel(const unsigned short* __restrict__ Xb,
                  const float* __restrict__ W1,
                  const float* __restrict__ W3,
                  const int* __restrict__ counts,
                  const int* __restrict__ offsets,
                  const int* __restrict__ btok,
                  unsigned short* __restrict__ hbuf) {
    const int e = blockIdx.z;
    const int ne = counts[e];
    const int mt = blockIdx.y;
    if (mt * 128 >= ne) return;
    const int nt = blockIdx.x;
    const int off = offsets[e];

    __shared__ unsigned short sA[128][32];
    __shared__ unsigned short sB1[128][32];
    __shared__ unsigned short sB3[128][32];
    __shared__ int s_tok[128];

    const int tid = threadIdx.x;
    if (tid < 128) {
        int slot = mt * 128 + tid;
        s_tok[tid] = (slot < ne) ? btok[off + slot] : -1;
    }

    const float* __restrict__ pB1 = W1 + (size_t)e * I_DIM * H_DIM + (size_t)(nt * 128) * H_DIM;
    const float* __restrict__ pB3 = W3 + (size_t)e * I_DIM * H_DIM + (size_t)(nt * 128) * H_DIM;

    const int lane = tid & 63;
    const int wv = tid >> 6;
    const int wm = (wv >> 1) << 6;
    const int wn = (wv & 1) << 6;
    const int q = lane >> 4;
    const int c = lane & 15;

    f32x4 accg[4][4], accu[4][4];
    const f32x4 zero = {0.0f, 0.0f, 0.0f, 0.0f};
    #pragma unroll
    for (int i = 0; i < 4; ++i)
        #pragma unroll
        for (int j = 0; j < 4; ++j) { accg[i][j] = zero; accu[i][j] = zero; }

    const int srow = tid >> 2;          // 0..63
    const int schunk = (tid & 3) * 8;   // element offset (8 elems = 16B)

    for (int kt = 0; kt < H_DIM; kt += 32) {
        __syncthreads();
        #pragma unroll
        for (int p = 0; p < 2; ++p) {
            int r = srow + p * 64;
            int tok = s_tok[r];
            u16x8 av = {0, 0, 0, 0, 0, 0, 0, 0};
            if (tok >= 0)
                av = *(const u16x8*)(Xb + (size_t)tok * H_DIM + kt + schunk);
            *(u16x8*)(&sA[r][schunk]) = av;

            const float* b1 = pB1 + (size_t)r * H_DIM + kt + schunk;
            float4 x0 = *(const float4*)(b1);
            float4 x1 = *(const float4*)(b1 + 4);
            u16x8 bv;
            bv[0] = f2bf(x0.x); bv[1] = f2bf(x0.y); bv[2] = f2bf(x0.z); bv[3] = f2bf(x0.w);
            bv[4] = f2bf(x1.x); bv[5] = f2bf(x1.y); bv[6] = f2bf(x1.z); bv[7] = f2bf(x1.w);
            *(u16x8*)(&sB1[r][schunk]) = bv;

            const float* b3 = pB3 + (size_t)r * H_DIM + kt + schunk;
            float4 y0 = *(const float4*)(b3);
            float4 y1 = *(const float4*)(b3 + 4);
            u16x8 cv;
            cv[0] = f2bf(y0.x); cv[1] = f2bf(y0.y); cv[2] = f2bf(y0.z); cv[3] = f2bf(y0.w);
            cv[4] = f2bf(y1.x); cv[5] = f2bf(y1.y); cv[6] = f2bf(y1.z); cv[7] = f2bf(y1.w);
            *(u16x8*)(&sB3[r][schunk]) = cv;
        }
        __syncthreads();

        bf16x8 af[4], b1f[4], b3f[4];
        #pragma unroll
        for (int i = 0; i < 4; ++i)
            af[i] = *(const bf16x8*)(&sA[wm + i * 16 + c][q * 8]);
        #pragma unroll
        for (int j = 0; j < 4; ++j) {
            b1f[j] = *(const bf16x8*)(&sB1[wn + j * 16 + c][q * 8]);
            b3f[j] = *(const bf16x8*)(&sB3[wn + j * 16 + c][q * 8]);
        }
        #pragma unroll
        for (int i = 0; i < 4; ++i)
            #pragma unroll
            for (int j = 0; j < 4; ++j) {
                accg[i][j] = __builtin_amdgcn_mfma_f32_16x16x32_bf16(af[i], b1f[j], accg[i][j], 0, 0, 0);
                accu[i][j] = __builtin_amdgcn_mfma_f32_16x16x32_bf16(af[i], b3f[j], accu[i][j], 0, 0, 0);
            }
    }

    // epilogue: h = silu(gate) * up  -> bf16
    #pragma unroll
    for (int i = 0; i < 4; ++i) {
        #pragma unroll
        for (int r = 0; r < 4; ++r) {
            int mloc = wm + i * 16 + q * 4 + r;
            int slot = mt * 128 + mloc;
            if (slot < ne) {
                size_t rowbase = (size_t)(off + slot) * I_DIM + nt * 128 + wn;
                #pragma unroll
                for (int j = 0; j < 4; ++j) {
                    float g = accg[i][j][r];
                    float u = accu[i][j][r];
                    float val = (g / (1.0f + __expf(-g))) * u;
                    hbuf[rowbase + j * 16 + c] = f2bf(val);
                }
            }
        }
    }
}

// ---------------- GEMM2: y = h @ W2^T, scatter-accumulate into out -----------
__global__ __launch_bounds__(256, 2)
void gemm2_kernel(const unsigned short* __restrict__ hbuf,
                  const float* __restrict__ W2,
                  const int* __restrict__ counts,
                  const int* __restrict__ offsets,
                  const int* __restrict__ btok,
                  const float* __restrict__ bw,
                  float* __restrict__ out) {
    const int e = blockIdx.z;
    const int ne = counts[e];
    const int mt = blockIdx.y;
    if (mt * 128 >= ne) return;
    const int nt = blockIdx.x;
    const int off = offsets[e];

    __shared__ unsigned short sA[128][32];
    __shared__ unsigned short sB[128][32];

    const int tid = threadIdx.x;
    const int lane = tid & 63;
    const int wv = tid >> 6;
    const int wm = (wv >> 1) << 6;
    const int wn = (wv & 1) << 6;
    const int q = lane >> 4;
    const int c = lane & 15;

    const float* __restrict__ pB = W2 + (size_t)e * H_DIM * I_DIM + (size_t)(nt * 128) * I_DIM;

    f32x4 acc[4][4];
    const f32x4 zero = {0.0f, 0.0f, 0.0f, 0.0f};
    #pragma unroll
    for (int i = 0; i < 4; ++i)
        #pragma unroll
        for (int j = 0; j < 4; ++j) acc[i][j] = zero;

    const int srow = tid >> 2;
    const int schunk = (tid & 3) * 8;

    for (int kt = 0; kt < I_DIM; kt += 32) {
        __syncthreads();
        #pragma unroll
        for (int p = 0; p < 2; ++p) {
            int r = srow + p * 64;
            int slot = mt * 128 + r;
            u16x8 av = {0, 0, 0, 0, 0, 0, 0, 0};
            if (slot < ne)
                av = *(const u16x8*)(hbuf + (size_t)(off + slot) * I_DIM + kt + schunk);
            *(u16x8*)(&sA[r][schunk]) = av;

            const float* b = pB + (size_t)r * I_DIM + kt + schunk;
            float4 x0 = *(const float4*)(b);
            float4 x1 = *(const float4*)(b + 4);
            u16x8 bv;
            bv[0] = f2bf(x0.x); bv[1] = f2bf(x0.y); bv[2] = f2bf(x0.z); bv[3] = f2bf(x0.w);
            bv[4] = f2bf(x1.x); bv[5] = f2bf(x1.y); bv[6] = f2bf(x1.z); bv[7] = f2bf(x1.w);
            *(u16x8*)(&sB[r][schunk]) = bv;
        }
        __syncthreads();

        bf16x8 af[4], bfr[4];
        #pragma unroll
        for (int i = 0; i < 4; ++i)
            af[i] = *(const bf16x8*)(&sA[wm + i * 16 + c][q * 8]);
        #pragma unroll
        for (int j = 0; j < 4; ++j)
            bfr[j] = *(const bf16x8*)(&sB[wn + j * 16 + c][q * 8]);
        #pragma unroll
        for (int i = 0; i < 4; ++i)
            #pragma unroll
            for (int j = 0; j < 4; ++j)
                acc[i][j] = __builtin_amdgcn_mfma_f32_16x16x32_bf16(af[i], bfr[j], acc[i][j], 0, 0, 0);
    }

    #pragma unroll
    for (int i = 0; i < 4; ++i) {
        #pragma unroll
        for (int r = 0; r < 4; ++r) {
            int mloc = wm + i * 16 + q * 4 + r;
            int slot = mt * 128 + mloc;
            if (slot < ne) {
                int tok = btok[off + slot];
                float wgt = bw[off + slot];
                float* obase = out + (size_t)tok * H_DIM + nt * 128 + wn;
                #pragma unroll
                for (int j = 0; j < 4; ++j)
                    atomicAdd(obase + j * 16 + c, wgt * acc[i][j][r]);
            }
        }
    }
}

extern "C" void kernel_launch(void* const* d_in, const int* in_sizes, int n_in,
                              void* d_out, int out_size, void* d_ws, size_t ws_size,
                              hipStream_t stream) {
    const float* hs = (const float*)d_in[0];   // [T, H]
    const float* rl = (const float*)d_in[1];   // [T, E]
    const float* w1 = (const float*)d_in[2];   // [E, I, H]
    const float* w3 = (const float*)d_in[3];   // [E, I, H]
    const float* w2 = (const float*)d_in[4];   // [E, H, I]
    float* out = (float*)d_out;

    char* ws = (char*)d_ws;
    int*   counts  = (int*)(ws);
    int*   offsets = (int*)(ws + 64);
    int*   btok    = (int*)(ws + 1024);                       // 8192 ints
    float* bw      = (float*)(ws + 1024 + 8192 * 4);          // 8192 floats
    unsigned short* Xb   = (unsigned short*)(ws + (1 << 20));            // 16 MB bf16 [T,H]
    unsigned short* hbuf = (unsigned short*)(ws + ((size_t)32 << 20));   // 64 MB bf16 [T*2, I]

    hipMemsetAsync(out, 0, (size_t)T_TOK * H_DIM * sizeof(float), stream);

    routing_kernel<<<1, 256, 0, stream>>>(rl, counts, offsets, btok, bw);

    int n4 = T_TOK * H_DIM / 4;
    cvt_kernel<<<n4 / 256, 256, 0, stream>>>(hs, Xb);

    gemm1_kernel<<<dim3(I_DIM / 128, T_TOK / 128, N_EXP), 256, 0, stream>>>(
        Xb, w1, w3, counts, offsets, btok, hbuf);

    gemm2_kernel<<<dim3(H_DIM / 128, T_TOK / 128, N_EXP), 256, 0, stream>>>(
        hbuf, w2, counts, offsets, btok, bw, out);
}

// Round 2
// 1371.837 us; speedup vs baseline: 1.2077x; 1.2077x over previous
//
#include <hip/hip_runtime.h>
#include <stdint.h>

#define T_TOK 4096
#define H_DIM 2048
#define I_DIM 4096
#define N_EXP 8

typedef __attribute__((ext_vector_type(8))) short bf16x8;     // MFMA A/B frag (8 bf16)
typedef __attribute__((ext_vector_type(4))) float f32x4;      // MFMA C/D frag
typedef __attribute__((ext_vector_type(8))) unsigned short u16x8;

__device__ __forceinline__ unsigned short f2bf(float x) {
    union { float f; unsigned u; } v; v.f = x;
    unsigned r = v.u + 0x7FFF + ((v.u >> 16) & 1);   // RNE
    return (unsigned short)(r >> 16);
}

// Direct global->LDS async copy, 16B per lane. LDS dest = wave-uniform base + lane*16.
__device__ __forceinline__ void async_cp16(const void* g, const unsigned short* lds_base) {
    __builtin_amdgcn_global_load_lds(
        (const __attribute__((address_space(1))) unsigned*)g,
        (__attribute__((address_space(3))) unsigned*)(unsigned)(uintptr_t)lds_base,
        16, 0, 0);
}

// ---------------- routing: top-2 + softmax + bucketize (single block) ----------
__global__ void routing_kernel(const float* __restrict__ logits,
                               int* __restrict__ counts, int* __restrict__ offsets,
                               int* __restrict__ btok, float* __restrict__ bw,
                               int* __restrict__ tok2slot) {
    __shared__ int s_cnt[N_EXP];
    __shared__ int s_off[N_EXP];
    __shared__ int s_cur[N_EXP];
    const int tid = threadIdx.x;   // 256 threads, 16 tokens each
    if (tid < N_EXP) s_cnt[tid] = 0;
    __syncthreads();

    int e0a[16], e1a[16]; float w0a[16], w1a[16];
    #pragma unroll
    for (int it = 0; it < 16; ++it) {
        int t = tid + it * 256;
        float l[8];
        #pragma unroll
        for (int e = 0; e < 8; ++e) l[e] = logits[t * 8 + e];
        int b0 = 0; float v0 = l[0];
        #pragma unroll
        for (int e = 1; e < 8; ++e) if (l[e] > v0) { v0 = l[e]; b0 = e; }
        int b1 = (b0 == 0) ? 1 : 0; float v1 = l[b1];
        #pragma unroll
        for (int e = 0; e < 8; ++e) if (e != b0 && l[e] > v1) { v1 = l[e]; b1 = e; }
        float w0 = 1.0f / (1.0f + __expf(v1 - v0));
        e0a[it] = b0; e1a[it] = b1; w0a[it] = w0; w1a[it] = 1.0f - w0;
        atomicAdd(&s_cnt[b0], 1);
        atomicAdd(&s_cnt[b1], 1);
    }
    __syncthreads();
    if (tid == 0) {
        int acc = 0;
        for (int e = 0; e < N_EXP; ++e) { s_off[e] = acc; s_cur[e] = acc; acc += s_cnt[e]; }
    }
    __syncthreads();
    if (tid < N_EXP) { counts[tid] = s_cnt[tid]; offsets[tid] = s_off[tid]; }
    #pragma unroll
    for (int it = 0; it < 16; ++it) {
        int t = tid + it * 256;
        int p0 = atomicAdd(&s_cur[e0a[it]], 1);
        btok[p0] = t; bw[p0] = w0a[it];
        int p1 = atomicAdd(&s_cur[e1a[it]], 1);
        btok[p1] = t; bw[p1] = w1a[it];
        tok2slot[2 * t] = p0;
        tok2slot[2 * t + 1] = p1;
    }
}

// ---------------- fp32 -> bf16 convert (generic) -----------------------------
__global__ void cvt_kernel(const float* __restrict__ x, unsigned short* __restrict__ xb) {
    int i = blockIdx.x * blockDim.x + threadIdx.x;   // over float4s
    float4 v = ((const float4*)x)[i];
    ushort4 o;
    o.x = f2bf(v.x); o.y = f2bf(v.y); o.z = f2bf(v.z); o.w = f2bf(v.w);
    ((ushort4*)xb)[i] = o;
}

// =====================  PATH A: preconverted bf16 weights ====================

// GEMM1: h[slot, i] = silu(x@W1^T) * (x@W3^T), 128x128 tiles, async LDS staging.
__global__ __launch_bounds__(256, 2)
void gemm1f_kernel(const unsigned short* __restrict__ Xb,
                   const unsigned short* __restrict__ W1b,
                   const unsigned short* __restrict__ W3b,
                   const int* __restrict__ counts,
                   const int* __restrict__ offsets,
                   const int* __restrict__ btok,
                   unsigned short* __restrict__ hbuf) {
    const int e = blockIdx.z;
    const int ne = counts[e];
    const int mt = blockIdx.y;
    if (mt * 128 >= ne) return;
    const int nt = blockIdx.x;
    const int off = offsets[e];

    __shared__ unsigned short sA[128 * 32];
    __shared__ unsigned short sB1[128 * 32];
    __shared__ unsigned short sB3[128 * 32];
    __shared__ int s_tok[128];

    const int tid = threadIdx.x;
    if (tid < 128) {
        int slot = mt * 128 + tid;
        s_tok[tid] = btok[off + ((slot < ne) ? slot : 0)];   // clamp OOB rows (masked in epilogue)
    }
    __syncthreads();

    const int lane = tid & 63;
    const int wv = tid >> 6;
    const int wm = (wv >> 1) << 6;
    const int wn = (wv & 1) << 6;
    const int q = lane >> 4;
    const int c = lane & 15;

    // staging geometry: wave wv stages rows [32wv, 32wv+32) of each tile,
    // as two 16-row chunks (1 KB each). lane i -> row chunkbase + i/4, elems (i%4)*8.
    const int srow = wv * 32 + (lane >> 2);
    const int cc = (lane & 3) * 8;

    const unsigned short* gA0 = Xb + (size_t)s_tok[srow] * H_DIM + cc;
    const unsigned short* gA1 = Xb + (size_t)s_tok[srow + 16] * H_DIM + cc;
    const size_t wrow = (size_t)e * I_DIM + nt * 128 + srow;
    const unsigned short* gW1a = W1b + wrow * H_DIM + cc;
    const unsigned short* gW1b_ = W1b + (wrow + 16) * H_DIM + cc;
    const unsigned short* gW3a = W3b + wrow * H_DIM + cc;
    const unsigned short* gW3b_ = W3b + (wrow + 16) * H_DIM + cc;

    const unsigned short* dA0 = &sA[1024 * wv];
    const unsigned short* dA1 = &sA[1024 * wv + 512];
    const unsigned short* dB1a = &sB1[1024 * wv];
    const unsigned short* dB1b = &sB1[1024 * wv + 512];
    const unsigned short* dB3a = &sB3[1024 * wv];
    const unsigned short* dB3b = &sB3[1024 * wv + 512];

    f32x4 accg[4][4], accu[4][4];
    const f32x4 zero = {0.0f, 0.0f, 0.0f, 0.0f};
    #pragma unroll
    for (int i = 0; i < 4; ++i)
        #pragma unroll
        for (int j = 0; j < 4; ++j) { accg[i][j] = zero; accu[i][j] = zero; }

    for (int kt = 0; kt < H_DIM; kt += 32) {
        __syncthreads();
        async_cp16(gA0 + kt, dA0);
        async_cp16(gA1 + kt, dA1);
        async_cp16(gW1a + kt, dB1a);
        async_cp16(gW1b_ + kt, dB1b);
        async_cp16(gW3a + kt, dB3a);
        async_cp16(gW3b_ + kt, dB3b);
        __syncthreads();

        bf16x8 af[4], b1f[4], b3f[4];
        #pragma unroll
        for (int i = 0; i < 4; ++i)
            af[i] = *(const bf16x8*)(&sA[(wm + i * 16 + c) * 32 + q * 8]);
        #pragma unroll
        for (int j = 0; j < 4; ++j) {
            b1f[j] = *(const bf16x8*)(&sB1[(wn + j * 16 + c) * 32 + q * 8]);
            b3f[j] = *(const bf16x8*)(&sB3[(wn + j * 16 + c) * 32 + q * 8]);
        }
        #pragma unroll
        for (int i = 0; i < 4; ++i)
            #pragma unroll
            for (int j = 0; j < 4; ++j) {
                accg[i][j] = __builtin_amdgcn_mfma_f32_16x16x32_bf16(af[i], b1f[j], accg[i][j], 0, 0, 0);
                accu[i][j] = __builtin_amdgcn_mfma_f32_16x16x32_bf16(af[i], b3f[j], accu[i][j], 0, 0, 0);
            }
    }

    #pragma unroll
    for (int i = 0; i < 4; ++i) {
        #pragma unroll
        for (int r = 0; r < 4; ++r) {
            int mloc = wm + i * 16 + q * 4 + r;
            int slot = mt * 128 + mloc;
            if (slot < ne) {
                size_t rowbase = (size_t)(off + slot) * I_DIM + nt * 128 + wn;
                #pragma unroll
                for (int j = 0; j < 4; ++j) {
                    float g = accg[i][j][r];
                    float u = accu[i][j][r];
                    float val = (g / (1.0f + __expf(-g))) * u;
                    hbuf[rowbase + j * 16 + c] = f2bf(val);
                }
            }
        }
    }
}

// GEMM2: y[slot, h] = h[slot] @ W2^T -> ybuf (fp32, plain stores)
__global__ __launch_bounds__(256, 2)
void gemm2f_kernel(const unsigned short* __restrict__ hbuf,
                   const unsigned short* __restrict__ W2b,
                   const int* __restrict__ counts,
                   const int* __restrict__ offsets,
                   float* __restrict__ ybuf) {
    const int e = blockIdx.z;
    const int ne = counts[e];
    const int mt = blockIdx.y;
    if (mt * 128 >= ne) return;
    const int nt = blockIdx.x;
    const int off = offsets[e];

    __shared__ unsigned short sA[128 * 32];
    __shared__ unsigned short sB[128 * 32];

    const int tid = threadIdx.x;
    const int lane = tid & 63;
    const int wv = tid >> 6;
    const int wm = (wv >> 1) << 6;
    const int wn = (wv & 1) << 6;
    const int q = lane >> 4;
    const int c = lane & 15;

    const int srow = wv * 32 + (lane >> 2);
    const int cc = (lane & 3) * 8;

    int slotA0 = mt * 128 + srow;      if (slotA0 >= ne) slotA0 = ne - 1;
    int slotA1 = mt * 128 + srow + 16; if (slotA1 >= ne) slotA1 = ne - 1;
    const unsigned short* gA0 = hbuf + (size_t)(off + slotA0) * I_DIM + cc;
    const unsigned short* gA1 = hbuf + (size_t)(off + slotA1) * I_DIM + cc;
    const size_t wrow = (size_t)e * H_DIM + nt * 128 + srow;
    const unsigned short* gB0 = W2b + wrow * I_DIM + cc;
    const unsigned short* gB1 = W2b + (wrow + 16) * I_DIM + cc;

    const unsigned short* dA0 = &sA[1024 * wv];
    const unsigned short* dA1 = &sA[1024 * wv + 512];
    const unsigned short* dB0 = &sB[1024 * wv];
    const unsigned short* dB1 = &sB[1024 * wv + 512];

    f32x4 acc[4][4];
    const f32x4 zero = {0.0f, 0.0f, 0.0f, 0.0f};
    #pragma unroll
    for (int i = 0; i < 4; ++i)
        #pragma unroll
        for (int j = 0; j < 4; ++j) acc[i][j] = zero;

    for (int kt = 0; kt < I_DIM; kt += 32) {
        __syncthreads();
        async_cp16(gA0 + kt, dA0);
        async_cp16(gA1 + kt, dA1);
        async_cp16(gB0 + kt, dB0);
        async_cp16(gB1 + kt, dB1);
        __syncthreads();

        bf16x8 af[4], bfr[4];
        #pragma unroll
        for (int i = 0; i < 4; ++i)
            af[i] = *(const bf16x8*)(&sA[(wm + i * 16 + c) * 32 + q * 8]);
        #pragma unroll
        for (int j = 0; j < 4; ++j)
            bfr[j] = *(const bf16x8*)(&sB[(wn + j * 16 + c) * 32 + q * 8]);
        #pragma unroll
        for (int i = 0; i < 4; ++i)
            #pragma unroll
            for (int j = 0; j < 4; ++j)
                acc[i][j] = __builtin_amdgcn_mfma_f32_16x16x32_bf16(af[i], bfr[j], acc[i][j], 0, 0, 0);
    }

    #pragma unroll
    for (int i = 0; i < 4; ++i) {
        #pragma unroll
        for (int r = 0; r < 4; ++r) {
            int mloc = wm + i * 16 + q * 4 + r;
            int slot = mt * 128 + mloc;
            if (slot < ne) {
                float* obase = ybuf + (size_t)(off + slot) * H_DIM + nt * 128 + wn;
                #pragma unroll
                for (int j = 0; j < 4; ++j)
                    obase[j * 16 + c] = acc[i][j][r];
            }
        }
    }
}

// combine: out[t] = w0 * y[slot0] + w1 * y[slot1]
__global__ void combine_kernel(const float* __restrict__ ybuf,
                               const float* __restrict__ bw,
                               const int* __restrict__ tok2slot,
                               float* __restrict__ out) {
    int i = blockIdx.x * blockDim.x + threadIdx.x;   // over float4 of out
    int t = i >> 9;            // H/4 = 512
    int h4 = i & 511;
    int p0 = tok2slot[2 * t], p1 = tok2slot[2 * t + 1];
    float w0 = bw[p0], w1 = bw[p1];
    float4 a = ((const float4*)(ybuf + (size_t)p0 * H_DIM))[h4];
    float4 b = ((const float4*)(ybuf + (size_t)p1 * H_DIM))[h4];
    float4 o;
    o.x = w0 * a.x + w1 * b.x;
    o.y = w0 * a.y + w1 * b.y;
    o.z = w0 * a.z + w1 * b.z;
    o.w = w0 * a.w + w1 * b.w;
    ((float4*)(out + (size_t)t * H_DIM))[h4] = o;
}

// =====================  PATH B: fallback (fp32 weights in-loop) ==============

__global__ __launch_bounds__(256, 2)
void gemm1_kernel(const unsigned short* __restrict__ Xb,
                  const float* __restrict__ W1,
                  const float* __restrict__ W3,
                  const int* __restrict__ counts,
                  const int* __restrict__ offsets,
                  const int* __restrict__ btok,
                  unsigned short* __restrict__ hbuf) {
    const int e = blockIdx.z;
    const int ne = counts[e];
    const int mt = blockIdx.y;
    if (mt * 128 >= ne) return;
    const int nt = blockIdx.x;
    const int off = offsets[e];

    __shared__ unsigned short sA[128][32];
    __shared__ unsigned short sB1[128][32];
    __shared__ unsigned short sB3[128][32];
    __shared__ int s_tok[128];

    const int tid = threadIdx.x;
    if (tid < 128) {
        int slot = mt * 128 + tid;
        s_tok[tid] = (slot < ne) ? btok[off + slot] : -1;
    }

    const float* __restrict__ pB1 = W1 + (size_t)e * I_DIM * H_DIM + (size_t)(nt * 128) * H_DIM;
    const float* __restrict__ pB3 = W3 + (size_t)e * I_DIM * H_DIM + (size_t)(nt * 128) * H_DIM;

    const int lane = tid & 63;
    const int wv = tid >> 6;
    const int wm = (wv >> 1) << 6;
    const int wn = (wv & 1) << 6;
    const int q = lane >> 4;
    const int c = lane & 15;

    f32x4 accg[4][4], accu[4][4];
    const f32x4 zero = {0.0f, 0.0f, 0.0f, 0.0f};
    #pragma unroll
    for (int i = 0; i < 4; ++i)
        #pragma unroll
        for (int j = 0; j < 4; ++j) { accg[i][j] = zero; accu[i][j] = zero; }

    const int srow = tid >> 2;
    const int schunk = (tid & 3) * 8;

    for (int kt = 0; kt < H_DIM; kt += 32) {
        __syncthreads();
        #pragma unroll
        for (int p = 0; p < 2; ++p) {
            int r = srow + p * 64;
            int tok = s_tok[r];
            u16x8 av = {0, 0, 0, 0, 0, 0, 0, 0};
            if (tok >= 0)
                av = *(const u16x8*)(Xb + (size_t)tok * H_DIM + kt + schunk);
            *(u16x8*)(&sA[r][schunk]) = av;

            const float* b1 = pB1 + (size_t)r * H_DIM + kt + schunk;
            float4 x0 = *(const float4*)(b1);
            float4 x1 = *(const float4*)(b1 + 4);
            u16x8 bv;
            bv[0] = f2bf(x0.x); bv[1] = f2bf(x0.y); bv[2] = f2bf(x0.z); bv[3] = f2bf(x0.w);
            bv[4] = f2bf(x1.x); bv[5] = f2bf(x1.y); bv[6] = f2bf(x1.z); bv[7] = f2bf(x1.w);
            *(u16x8*)(&sB1[r][schunk]) = bv;

            const float* b3 = pB3 + (size_t)r * H_DIM + kt + schunk;
            float4 y0 = *(const float4*)(b3);
            float4 y1 = *(const float4*)(b3 + 4);
            u16x8 cv;
            cv[0] = f2bf(y0.x); cv[1] = f2bf(y0.y); cv[2] = f2bf(y0.z); cv[3] = f2bf(y0.w);
            cv[4] = f2bf(y1.x); cv[5] = f2bf(y1.y); cv[6] = f2bf(y1.z); cv[7] = f2bf(y1.w);
            *(u16x8*)(&sB3[r][schunk]) = cv;
        }
        __syncthreads();

        bf16x8 af[4], b1f[4], b3f[4];
        #pragma unroll
        for (int i = 0; i < 4; ++i)
            af[i] = *(const bf16x8*)(&sA[wm + i * 16 + c][q * 8]);
        #pragma unroll
        for (int j = 0; j < 4; ++j) {
            b1f[j] = *(const bf16x8*)(&sB1[wn + j * 16 + c][q * 8]);
            b3f[j] = *(const bf16x8*)(&sB3[wn + j * 16 + c][q * 8]);
        }
        #pragma unroll
        for (int i = 0; i < 4; ++i)
            #pragma unroll
            for (int j = 0; j < 4; ++j) {
                accg[i][j] = __builtin_amdgcn_mfma_f32_16x16x32_bf16(af[i], b1f[j], accg[i][j], 0, 0, 0);
                accu[i][j] = __builtin_amdgcn_mfma_f32_16x16x32_bf16(af[i], b3f[j], accu[i][j], 0, 0, 0);
            }
    }

    #pragma unroll
    for (int i = 0; i < 4; ++i) {
        #pragma unroll
        for (int r = 0; r < 4; ++r) {
            int mloc = wm + i * 16 + q * 4 + r;
            int slot = mt * 128 + mloc;
            if (slot < ne) {
                size_t rowbase = (size_t)(off + slot) * I_DIM + nt * 128 + wn;
                #pragma unroll
                for (int j = 0; j < 4; ++j) {
                    float g = accg[i][j][r];
                    float u = accu[i][j][r];
                    float val = (g / (1.0f + __expf(-g))) * u;
                    hbuf[rowbase + j * 16 + c] = f2bf(val);
                }
            }
        }
    }
}

__global__ __launch_bounds__(256, 2)
void gemm2_kernel(const unsigned short* __restrict__ hbuf,
                  const float* __restrict__ W2,
                  const int* __restrict__ counts,
                  const int* __restrict__ offsets,
                  const int* __restrict__ btok,
                  const float* __restrict__ bw,
                  float* __restrict__ out) {
    const int e = blockIdx.z;
    const int ne = counts[e];
    const int mt = blockIdx.y;
    if (mt * 128 >= ne) return;
    const int nt = blockIdx.x;
    const int off = offsets[e];

    __shared__ unsigned short sA[128][32];
    __shared__ unsigned short sB[128][32];

    const int tid = threadIdx.x;
    const int lane = tid & 63;
    const int wv = tid >> 6;
    const int wm = (wv >> 1) << 6;
    const int wn = (wv & 1) << 6;
    const int q = lane >> 4;
    const int c = lane & 15;

    const float* __restrict__ pB = W2 + (size_t)e * H_DIM * I_DIM + (size_t)(nt * 128) * I_DIM;

    f32x4 acc[4][4];
    const f32x4 zero = {0.0f, 0.0f, 0.0f, 0.0f};
    #pragma unroll
    for (int i = 0; i < 4; ++i)
        #pragma unroll
        for (int j = 0; j < 4; ++j) acc[i][j] = zero;

    const int srow = tid >> 2;
    const int schunk = (tid & 3) * 8;

    for (int kt = 0; kt < I_DIM; kt += 32) {
        __syncthreads();
        #pragma unroll
        for (int p = 0; p < 2; ++p) {
            int r = srow + p * 64;
            int slot = mt * 128 + r;
            u16x8 av = {0, 0, 0, 0, 0, 0, 0, 0};
            if (slot < ne)
                av = *(const u16x8*)(hbuf + (size_t)(off + slot) * I_DIM + kt + schunk);
            *(u16x8*)(&sA[r][schunk]) = av;

            const float* b = pB + (size_t)r * I_DIM + kt + schunk;
            float4 x0 = *(const float4*)(b);
            float4 x1 = *(const float4*)(b + 4);
            u16x8 bv;
            bv[0] = f2bf(x0.x); bv[1] = f2bf(x0.y); bv[2] = f2bf(x0.z); bv[3] = f2bf(x0.w);
            bv[4] = f2bf(x1.x); bv[5] = f2bf(x1.y); bv[6] = f2bf(x1.z); bv[7] = f2bf(x1.w);
            *(u16x8*)(&sB[r][schunk]) = bv;
        }
        __syncthreads();

        bf16x8 af[4], bfr[4];
        #pragma unroll
        for (int i = 0; i < 4; ++i)
            af[i] = *(const bf16x8*)(&sA[wm + i * 16 + c][q * 8]);
        #pragma unroll
        for (int j = 0; j < 4; ++j)
            bfr[j] = *(const bf16x8*)(&sB[wn + j * 16 + c][q * 8]);
        #pragma unroll
        for (int i = 0; i < 4; ++i)
            #pragma unroll
            for (int j = 0; j < 4; ++j)
                acc[i][j] = __builtin_amdgcn_mfma_f32_16x16x32_bf16(af[i], bfr[j], acc[i][j], 0, 0, 0);
    }

    #pragma unroll
    for (int i = 0; i < 4; ++i) {
        #pragma unroll
        for (int r = 0; r < 4; ++r) {
            int mloc = wm + i * 16 + q * 4 + r;
            int slot = mt * 128 + mloc;
            if (slot < ne) {
                int tok = btok[off + slot];
                float wgt = bw[off + slot];
                float* obase = out + (size_t)tok * H_DIM + nt * 128 + wn;
                #pragma unroll
                for (int j = 0; j < 4; ++j)
                    atomicAdd(obase + j * 16 + c, wgt * acc[i][j][r]);
            }
        }
    }
}

// ============================================================================

extern "C" void kernel_launch(void* const* d_in, const int* in_sizes, int n_in,
                              void* d_out, int out_size, void* d_ws, size_t ws_size,
                              hipStream_t stream) {
    const float* hs = (const float*)d_in[0];   // [T, H]
    const float* rl = (const float*)d_in[1];   // [T, E]
    const float* w1 = (const float*)d_in[2];   // [E, I, H]
    const float* w3 = (const float*)d_in[3];   // [E, I, H]
    const float* w2 = (const float*)d_in[4];   // [E, H, I]
    float* out = (float*)d_out;

    char* ws = (char*)d_ws;
    // meta region (first 1 MB)
    int*   counts   = (int*)(ws);
    int*   offsets  = (int*)(ws + 256);
    int*   btok     = (int*)(ws + 4096);            // 8192 ints
    float* bw       = (float*)(ws + 36864);         // 8192 floats
    int*   tok2slot = (int*)(ws + 69632);           // 8192 ints

    const size_t MB = 1ull << 20;
    const size_t NEED_A = 529 * MB;

    if (ws_size >= NEED_A) {
        // -------- Path A: preconvert weights to bf16, async-staged GEMMs ----
        unsigned short* Xb   = (unsigned short*)(ws + 1 * MB);     // 16 MB
        unsigned short* hbuf = (unsigned short*)(ws + 17 * MB);    // 64 MB
        float*          ybuf = (float*)(ws + 81 * MB);             // 64 MB
        unsigned short* w1b  = (unsigned short*)(ws + 145 * MB);   // 128 MB
        unsigned short* w3b  = (unsigned short*)(ws + 273 * MB);   // 128 MB
        unsigned short* w2b  = (unsigned short*)(ws + 401 * MB);   // 128 MB

        routing_kernel<<<1, 256, 0, stream>>>(rl, counts, offsets, btok, bw, tok2slot);

        cvt_kernel<<<(T_TOK * H_DIM / 4) / 256, 256, 0, stream>>>(hs, Xb);
        int wn4 = N_EXP * I_DIM * H_DIM / 4;   // 16M float4 per weight tensor
        cvt_kernel<<<wn4 / 256, 256, 0, stream>>>(w1, w1b);
        cvt_kernel<<<wn4 / 256, 256, 0, stream>>>(w3, w3b);
        cvt_kernel<<<wn4 / 256, 256, 0, stream>>>(w2, w2b);

        gemm1f_kernel<<<dim3(I_DIM / 128, 64, N_EXP), 256, 0, stream>>>(
            Xb, w1b, w3b, counts, offsets, btok, hbuf);

        gemm2f_kernel<<<dim3(H_DIM / 128, 64, N_EXP), 256, 0, stream>>>(
            hbuf, w2b, counts, offsets, ybuf);

        combine_kernel<<<(T_TOK * (H_DIM / 4)) / 256, 256, 0, stream>>>(
            ybuf, bw, tok2slot, out);
    } else {
        // -------- Path B: fallback (known-good round-1 structure) -----------
        unsigned short* Xb   = (unsigned short*)(ws + 1 * MB);            // 16 MB
        unsigned short* hbuf = (unsigned short*)(ws + 32 * MB);           // 64 MB

        hipMemsetAsync(out, 0, (size_t)T_TOK * H_DIM * sizeof(float), stream);

        routing_kernel<<<1, 256, 0, stream>>>(rl, counts, offsets, btok, bw, tok2slot);

        cvt_kernel<<<(T_TOK * H_DIM / 4) / 256, 256, 0, stream>>>(hs, Xb);

        gemm1_kernel<<<dim3(I_DIM / 128, T_TOK / 128, N_EXP), 256, 0, stream>>>(
            Xb, w1, w3, counts, offsets, btok, hbuf);

        gemm2_kernel<<<dim3(H_DIM / 128, T_TOK / 128, N_EXP), 256, 0, stream>>>(
            hbuf, w2, counts, offsets, btok, bw, out);
    }
}